// Round 7
// baseline (197.539 us; speedup 1.0000x reference)
//
#include <hip/hip_runtime.h>

// SPD loss: 18-bin (9 class x 2 group) histogram over 16.7M int32 pairs + tiny epilogue.
// R0: LDS atomics 55us. R1: register hist 55us. R2: no global atomics 45us.
// R3: MLP burst, no change. R4: nt loads + pipeline -> 42us, occupancy 21% (VGPR 76).
// R5: occupancy rewrite FAILED correctness (absmax 1.8e-2) — unexplained; reverted.
// R6: R4's PROVEN arithmetic verbatim (cndmask acc0/acc1, row-major partials,
//     R4 finalize), geometry only: no pipeline (16 VGPR of load buffers, not 64),
//     grid 8192 x 256 thr = one 512-int4 window per block, aiming 8 waves/SIMD.
//     Butterfly reduces unpacked u32 pairs (overflow-proof for any grid >= 2).

#define N_CLASSES 9
#define N_GROUPS 2
#define NBINS (N_CLASSES * N_GROUPS)  // 18
#define ITEMS 2                       // int4 per array per thread per window (8 elems < 127 field cap)
#define BLOCK 256

typedef int v4i __attribute__((ext_vector_type(4)));

__device__ __forceinline__ void acc_item(int pv, int av,
                                         unsigned long long& acc0,
                                         unsigned long long& acc1) {
    unsigned long long inc = 1ull << (7 * pv);
    acc0 += (av == 0) ? inc : 0ull;
    acc1 += (av == 0) ? 0ull : inc;
}

__global__ __launch_bounds__(BLOCK) void spd_hist_kernel(
    const int* __restrict__ preds,
    const int* __restrict__ attrs,
    unsigned int* __restrict__ partials,  // [gridDim.x][NBINS] row-major (R4 layout)
    int n4, int n)
{
    __shared__ unsigned int lh0[N_CLASSES];
    __shared__ unsigned int lh1[N_CLASSES];
    if (threadIdx.x < N_CLASSES) { lh0[threadIdx.x] = 0u; lh1[threadIdx.x] = 0u; }
    __syncthreads();

    // per-thread packed totals: lo16 = group0, hi16 = group1 (R4 scheme)
    unsigned int cnt[N_CLASSES];
    #pragma unroll
    for (int p = 0; p < N_CLASSES; ++p) cnt[p] = 0u;

    const v4i* __restrict__ p4 = (const v4i*)preds;
    const v4i* __restrict__ a4 = (const v4i*)attrs;
    const int tid = (int)threadIdx.x;
    const int span = BLOCK * ITEMS;               // 512 int4 per block-window
    const int stride = gridDim.x * span;

    for (int S = blockIdx.x * span; S < n4; S += stride) {
        unsigned long long acc0 = 0ull, acc1 = 0ull;  // 9 fields x 7 bits, <=8/field per window

        if (S + span <= n4) {
            // all 4 independent 16-B loads issued before any use
            v4i p0 = __builtin_nontemporal_load(p4 + S + tid);
            v4i p1 = __builtin_nontemporal_load(p4 + S + tid + BLOCK);
            v4i a0 = __builtin_nontemporal_load(a4 + S + tid);
            v4i a1 = __builtin_nontemporal_load(a4 + S + tid + BLOCK);
            #pragma unroll
            for (int e = 0; e < 4; ++e) {
                acc_item(p0[e], a0[e], acc0, acc1);
                acc_item(p1[e], a1[e], acc0, acc1);
            }
        } else {
            for (int k = 0; k < ITEMS; ++k) {
                const int idx = S + tid + k * BLOCK;
                if (idx < n4) {
                    v4i pp = p4[idx];
                    v4i aa = a4[idx];
                    #pragma unroll
                    for (int e = 0; e < 4; ++e)
                        acc_item(pp[e], aa[e], acc0, acc1);
                }
            }
        }

        // flush 7-bit window into 16-bit packed totals (compile-time shifts)
        #pragma unroll
        for (int p = 0; p < N_CLASSES; ++p) {
            cnt[p] += ((unsigned int)(acc0 >> (7 * p)) & 127u)
                    | (((unsigned int)(acc1 >> (7 * p)) & 127u) << 16);
        }
    }

    // scalar remainder (n % 4), block 0 only: <=3 items
    if (blockIdx.x == 0) {
        for (int t = n4 * 4 + tid; t < n; t += BLOCK)
            cnt[preds[t]] += (attrs[t] == 0) ? 1u : 0x10000u;
    }

    // unpack BEFORE reduction: u32 butterfly is overflow-proof for any grid >= 2
    unsigned int c0[N_CLASSES], c1[N_CLASSES];
    #pragma unroll
    for (int p = 0; p < N_CLASSES; ++p) {
        c0[p] = cnt[p] & 0xFFFFu;
        c1[p] = cnt[p] >> 16;
    }

    #pragma unroll
    for (int m = 1; m < 64; m <<= 1) {
        #pragma unroll
        for (int p = 0; p < N_CLASSES; ++p) {
            c0[p] += __shfl_xor(c0[p], m, 64);
            c1[p] += __shfl_xor(c1[p], m, 64);
        }
    }

    if ((tid & 63) == 0) {
        #pragma unroll
        for (int p = 0; p < N_CLASSES; ++p) {
            atomicAdd(&lh0[p], c0[p]);
            atomicAdd(&lh1[p], c1[p]);
        }
    }
    __syncthreads();

    // R4's proven interleaved row-major store: partials[block][2c+g]
    if (tid < NBINS) {
        int c = tid >> 1;
        unsigned int v = (tid & 1) ? lh1[c] : lh0[c];
        partials[blockIdx.x * NBINS + tid] = v;
    }
}

__global__ __launch_bounds__(1024) void spd_finalize_kernel(
    const unsigned int* __restrict__ partials,
    float* __restrict__ out, int nblocks, double n_total)
{
    __shared__ double counts[NBINS];
    const int tid = threadIdx.x;

    if (tid < NBINS * 32) {
        const int bin = tid >> 5;
        const int j = tid & 31;
        unsigned int s = 0u;
        #pragma unroll 8
        for (int b = j; b < nblocks; b += 32)
            s += partials[b * NBINS + bin];
        #pragma unroll
        for (int m = 1; m < 32; m <<= 1)
            s += __shfl_xor(s, m, 32);
        if (j == 0) counts[bin] = (double)s;
    }
    __syncthreads();

    if (tid == 0) {
        double n1 = 0.0;
        #pragma unroll
        for (int c = 0; c < N_CLASSES; ++c)
            n1 += counts[c * N_GROUPS + 1];
        double n0 = n_total - n1;
        double acc = 0.0;
        #pragma unroll
        for (int c = 0; c < N_CLASSES; ++c) {
            double d = counts[c * N_GROUPS] / n0 - counts[c * N_GROUPS + 1] / n1;
            acc += d * d;
        }
        out[0] = (float)acc;
    }
}

extern "C" void kernel_launch(void* const* d_in, const int* in_sizes, int n_in,
                              void* d_out, int out_size, void* d_ws, size_t ws_size,
                              hipStream_t stream)
{
    const int* preds = (const int*)d_in[0];
    const int* attrs = (const int*)d_in[1];
    const int n = in_sizes[0];

    unsigned int* partials = (unsigned int*)d_ws;

    const int n4 = n / 4;
    const int span = BLOCK * ITEMS;                 // 512 int4 per block-window
    int grid = (n4 + span - 1) / span;              // 8192 at N=16.7M -> one window per block
    if (grid > 8192) grid = 8192;
    int max_grid = (int)(ws_size / (NBINS * sizeof(unsigned int)));
    if (grid > max_grid) grid = max_grid;
    if (grid < 1) grid = 1;

    spd_hist_kernel<<<grid, BLOCK, 0, stream>>>(preds, attrs, partials, n4, n);
    spd_finalize_kernel<<<1, 1024, 0, stream>>>(partials, (float*)d_out, grid, (double)n);
}

// Round 8
// 161.320 us; speedup vs baseline: 1.2245x; 1.2245x over previous
//
#include <hip/hip_runtime.h>
#include <cstdint>

// SPD loss: 18-bin (9 class x 2 group) histogram over 16.7M int32 pairs + tiny epilogue.
// R0: LDS atomics 55us. R1: register hist 55us. R2: no global atomics 45us.
// R3: MLP burst no change. R4: nt+pipeline 42us @ 21% occ. R6: occ 67% -> 50us.
//   => every VGPR-return load variant plateaus at ~3.2 TB/s aggregate read
//      (5.2 B/cy/CU): per-CU TCP miss-tracking limit, structure-independent.
// R7: switch read path entirely: global_load_lds DMA (m97 sustained ~22 B/cy/CU
//     through it). 4 KB tiles/array, double-buffered LDS, ds_read_b128 consume.
//     Arithmetic/butterfly/partials/finalize = R6 proven code verbatim.

#define N_CLASSES 9
#define N_GROUPS 2
#define NBINS (N_CLASSES * N_GROUPS)  // 18
#define BLOCK 256
#define TILE_INTS 1024                // per array per tile = 4 KB
#define TILE_I4 256                   // int4s per tile

typedef int v4i __attribute__((ext_vector_type(4)));

__device__ __forceinline__ void acc_item(int pv, int av,
                                         unsigned long long& acc0,
                                         unsigned long long& acc1) {
    unsigned long long inc = 1ull << (7 * pv);
    acc0 += (av == 0) ? inc : 0ull;
    acc1 += (av == 0) ? 0ull : inc;
}

__global__ __launch_bounds__(BLOCK) void spd_hist_kernel(
    const int* __restrict__ preds,
    const int* __restrict__ attrs,
    unsigned int* __restrict__ partials,  // [gridDim.x][NBINS] row-major
    int n4, int n, int ntiles)
{
    __shared__ v4i pbuf[2][TILE_I4];      // 2 x 4 KB, 16-B aligned
    __shared__ v4i abuf[2][TILE_I4];
    __shared__ unsigned int lh0[N_CLASSES];
    __shared__ unsigned int lh1[N_CLASSES];
    if (threadIdx.x < N_CLASSES) { lh0[threadIdx.x] = 0u; lh1[threadIdx.x] = 0u; }

    const int tid = (int)threadIdx.x;
    const int wave = tid >> 6;
    const int lane = tid & 63;

    // per-thread packed totals: lo16 = group0, hi16 = group1
    unsigned int cnt[N_CLASSES];
    #pragma unroll
    for (int p = 0; p < N_CLASSES; ++p) cnt[p] = 0u;

    // DMA one tile (both arrays) into buffer b.
    // Wave w moves 1 KB per array: global [T*4KB + w*1KB + lane*16, +16)
    // -> LDS base + w*1KB (per-lane placement = base + lane*16, HW-defined).
    auto prefetch = [&](int T, int b) {
        const int goff = T * TILE_INTS + wave * 256 + lane * 4;
        __builtin_amdgcn_global_load_lds(
            (const __attribute__((address_space(1))) int*)(preds + goff),
            (__attribute__((address_space(3))) int*)((char*)&pbuf[b][0] + wave * 1024),
            16, 0, 0);
        __builtin_amdgcn_global_load_lds(
            (const __attribute__((address_space(1))) int*)(attrs + goff),
            (__attribute__((address_space(3))) int*)((char*)&abuf[b][0] + wave * 1024),
            16, 0, 0);
    };

    int T = blockIdx.x;
    int buf = 0;
    bool have = (T < ntiles);
    if (have) prefetch(T, 0);

    while (have) {
        __syncthreads();                       // drains DMA for buf (vmcnt) + prior LDS reads
        const int Tn = T + (int)gridDim.x;
        const bool haven = (Tn < ntiles);
        if (haven) prefetch(Tn, buf ^ 1);      // in flight while we consume buf

        // consume tile: 4 ints per array per thread, conflict-free b128 reads
        v4i pp = pbuf[buf][tid];
        v4i aa = abuf[buf][tid];
        unsigned long long acc0 = 0ull, acc1 = 0ull;  // fields <= 4 per window
        #pragma unroll
        for (int e = 0; e < 4; ++e)
            acc_item(pp[e], aa[e], acc0, acc1);
        #pragma unroll
        for (int p = 0; p < N_CLASSES; ++p) {
            cnt[p] += ((unsigned int)(acc0 >> (7 * p)) & 127u)
                    | (((unsigned int)(acc1 >> (7 * p)) & 127u) << 16);
        }

        buf ^= 1; T = Tn; have = haven;
    }

    // remainder ints [ntiles*TILE_INTS, n): block 0, direct masked path
    if (blockIdx.x == 0) {
        for (int t = ntiles * TILE_INTS + tid; t < n; t += BLOCK)
            cnt[preds[t]] += (attrs[t] == 0) ? 1u : 0x10000u;
    }

    // unpack then u32 butterfly (overflow-proof), R6-proven
    unsigned int c0[N_CLASSES], c1[N_CLASSES];
    #pragma unroll
    for (int p = 0; p < N_CLASSES; ++p) {
        c0[p] = cnt[p] & 0xFFFFu;
        c1[p] = cnt[p] >> 16;
    }
    #pragma unroll
    for (int m = 1; m < 64; m <<= 1) {
        #pragma unroll
        for (int p = 0; p < N_CLASSES; ++p) {
            c0[p] += __shfl_xor(c0[p], m, 64);
            c1[p] += __shfl_xor(c1[p], m, 64);
        }
    }

    __syncthreads();   // lh0/lh1 init visible (init had no barrier after it)
    if ((tid & 63) == 0) {
        #pragma unroll
        for (int p = 0; p < N_CLASSES; ++p) {
            atomicAdd(&lh0[p], c0[p]);
            atomicAdd(&lh1[p], c1[p]);
        }
    }
    __syncthreads();

    if (tid < NBINS) {
        int c = tid >> 1;
        unsigned int v = (tid & 1) ? lh1[c] : lh0[c];
        partials[blockIdx.x * NBINS + tid] = v;
    }
}

__global__ __launch_bounds__(1024) void spd_finalize_kernel(
    const unsigned int* __restrict__ partials,
    float* __restrict__ out, int nblocks, double n_total)
{
    __shared__ double counts[NBINS];
    const int tid = threadIdx.x;

    if (tid < NBINS * 32) {
        const int bin = tid >> 5;
        const int j = tid & 31;
        unsigned int s = 0u;
        #pragma unroll 8
        for (int b = j; b < nblocks; b += 32)
            s += partials[b * NBINS + bin];
        #pragma unroll
        for (int m = 1; m < 32; m <<= 1)
            s += __shfl_xor(s, m, 32);
        if (j == 0) counts[bin] = (double)s;
    }
    __syncthreads();

    if (tid == 0) {
        double n1 = 0.0;
        #pragma unroll
        for (int c = 0; c < N_CLASSES; ++c)
            n1 += counts[c * N_GROUPS + 1];
        double n0 = n_total - n1;
        double acc = 0.0;
        #pragma unroll
        for (int c = 0; c < N_CLASSES; ++c) {
            double d = counts[c * N_GROUPS] / n0 - counts[c * N_GROUPS + 1] / n1;
            acc += d * d;
        }
        out[0] = (float)acc;
    }
}

extern "C" void kernel_launch(void* const* d_in, const int* in_sizes, int n_in,
                              void* d_out, int out_size, void* d_ws, size_t ws_size,
                              hipStream_t stream)
{
    const int* preds = (const int*)d_in[0];
    const int* attrs = (const int*)d_in[1];
    const int n = in_sizes[0];

    unsigned int* partials = (unsigned int*)d_ws;

    const int n4 = n / 4;
    const int ntiles = n4 / TILE_I4;                // full 4 KB tiles (16384 at N=16.7M)
    int grid = 2048;                                // 8 tiles/block, 8 blocks/CU
    if (grid > ntiles && ntiles > 0) grid = ntiles;
    int max_grid = (int)(ws_size / (NBINS * sizeof(unsigned int)));
    if (grid > max_grid) grid = max_grid;
    if (grid < 1) grid = 1;

    spd_hist_kernel<<<grid, BLOCK, 0, stream>>>(preds, attrs, partials, n4, n, ntiles);
    spd_finalize_kernel<<<1, 1024, 0, stream>>>(partials, (float*)d_out, grid, (double)n);
}

// Round 9
// 157.270 us; speedup vs baseline: 1.2560x; 1.0258x over previous
//
#include <hip/hip_runtime.h>

// SPD loss: 18-bin (9 class x 2 group) histogram over 16.7M int32 pairs + tiny epilogue.
// Session findings:
//   R0 LDS atomics 55us -> R1 register hist 55us -> R2 no global atomics 45us
//   R3 16-deep MLP burst: no change. R4 nt+2-deep pipeline, grid 1024: 42us (BEST, 21% occ)
//   R5 occupancy rewrite: correctness FAIL (reverted). R6 occ 67%: 50us (slower).
//   R7 global_load_lds DMA double-buffer: 50us (same plateau).
// Conclusion: aggregate read rate pinned at ~2.7-3.2 TB/s = ~5 B/cy/CU across ALL
// structures == the read component of m13's copy bench (6.29 TB/s total). The
// kernel is bound by per-CU memory-ingest (TCP line-request) rate, independent of
// occupancy/MLP/path. 134 MB / 256 CU / 5.1 B/cy ~= 43 us == R4's measurement.
// R8: restore R4 verbatim (best measured).

#define N_CLASSES 9
#define N_GROUPS 2
#define NBINS (N_CLASSES * N_GROUPS)  // 18
#define ITEMS 4                       // int4-pairs per thread per stage (16 elems < 127 field cap)
#define BLOCK 256

typedef int v4i __attribute__((ext_vector_type(4)));

__device__ __forceinline__ void acc_item(int pv, int av,
                                         unsigned long long& acc0,
                                         unsigned long long& acc1) {
    unsigned long long inc = 1ull << (7 * pv);
    acc0 += (av == 0) ? inc : 0ull;
    acc1 += (av == 0) ? 0ull : inc;
}

__global__ __launch_bounds__(BLOCK) void spd_hist_kernel(
    const int* __restrict__ preds,
    const int* __restrict__ attrs,
    unsigned int* __restrict__ partials,  // [gridDim.x][NBINS]
    int n4, int n)
{
    __shared__ unsigned int lh0[N_CLASSES];
    __shared__ unsigned int lh1[N_CLASSES];
    if (threadIdx.x < N_CLASSES) { lh0[threadIdx.x] = 0u; lh1[threadIdx.x] = 0u; }
    __syncthreads();

    unsigned int cnt[N_CLASSES];
    #pragma unroll
    for (int p = 0; p < N_CLASSES; ++p) cnt[p] = 0u;

    const v4i* __restrict__ p4 = (const v4i*)preds;
    const v4i* __restrict__ a4 = (const v4i*)attrs;
    const int tid = (int)threadIdx.x;

    const int span = BLOCK * ITEMS;            // int4s per block-stage
    const int stride = gridDim.x * span;

    v4i pb[2][ITEMS], ab[2][ITEMS];

    int S = blockIdx.x * span;
    int buf = 0;
    bool have = (S + span <= n4);

    if (have) {
        const int s = S + tid;
        #pragma unroll
        for (int k = 0; k < ITEMS; ++k) pb[0][k] = __builtin_nontemporal_load(p4 + s + k * BLOCK);
        #pragma unroll
        for (int k = 0; k < ITEMS; ++k) ab[0][k] = __builtin_nontemporal_load(a4 + s + k * BLOCK);
    }

    while (have) {
        const int Snext = S + stride;
        const bool havenext = (Snext + span <= n4);
        if (havenext) {
            const int s = Snext + tid;
            #pragma unroll
            for (int k = 0; k < ITEMS; ++k) pb[buf ^ 1][k] = __builtin_nontemporal_load(p4 + s + k * BLOCK);
            #pragma unroll
            for (int k = 0; k < ITEMS; ++k) ab[buf ^ 1][k] = __builtin_nontemporal_load(a4 + s + k * BLOCK);
        }

        // consume current stage: 7-bit field register histogram (<=16 per field)
        unsigned long long acc0 = 0ull, acc1 = 0ull;
        #pragma unroll
        for (int k = 0; k < ITEMS; ++k) {
            acc_item(pb[buf][k].x, ab[buf][k].x, acc0, acc1);
            acc_item(pb[buf][k].y, ab[buf][k].y, acc0, acc1);
            acc_item(pb[buf][k].z, ab[buf][k].z, acc0, acc1);
            acc_item(pb[buf][k].w, ab[buf][k].w, acc0, acc1);
        }
        #pragma unroll
        for (int p = 0; p < N_CLASSES; ++p) {
            cnt[p] += ((unsigned int)(acc0 >> (7 * p)) & 127u)
                    | (((unsigned int)(acc1 >> (7 * p)) & 127u) << 16);
        }

        buf ^= 1;
        S = Snext;
        have = havenext;
    }

    // at most one partial stage per block: S < n4 but S + span > n4
    if (S < n4) {
        unsigned long long acc0 = 0ull, acc1 = 0ull;
        for (int k = 0; k < ITEMS; ++k) {
            const int idx = S + tid + k * BLOCK;
            if (idx < n4) {
                v4i pp = p4[idx];
                v4i aa = a4[idx];
                acc_item(pp.x, aa.x, acc0, acc1);
                acc_item(pp.y, aa.y, acc0, acc1);
                acc_item(pp.z, aa.z, acc0, acc1);
                acc_item(pp.w, aa.w, acc0, acc1);
            }
        }
        #pragma unroll
        for (int p = 0; p < N_CLASSES; ++p) {
            cnt[p] += ((unsigned int)(acc0 >> (7 * p)) & 127u)
                    | (((unsigned int)(acc1 >> (7 * p)) & 127u) << 16);
        }
    }

    // scalar remainder (n % 4), block 0 only: <=3 items
    if (blockIdx.x == 0) {
        for (int t = n4 * 4 + tid; t < n; t += BLOCK)
            cnt[preds[t]] += (attrs[t] == 0) ? 1u : 0x10000u;
    }

    // wave-64 butterfly; 16-bit halves <= 64 * items/thread (4096) << 65536
    #pragma unroll
    for (int m = 1; m < 64; m <<= 1) {
        #pragma unroll
        for (int p = 0; p < N_CLASSES; ++p)
            cnt[p] += __shfl_xor(cnt[p], m, 64);
    }

    if ((tid & 63) == 0) {
        #pragma unroll
        for (int p = 0; p < N_CLASSES; ++p) {
            atomicAdd(&lh0[p], cnt[p] & 0xFFFFu);
            atomicAdd(&lh1[p], cnt[p] >> 16);
        }
    }
    __syncthreads();

    if (tid < NBINS) {
        int c = tid >> 1;
        unsigned int v = (tid & 1) ? lh1[c] : lh0[c];
        partials[blockIdx.x * NBINS + tid] = v;
    }
}

__global__ __launch_bounds__(1024) void spd_finalize_kernel(
    const unsigned int* __restrict__ partials,
    float* __restrict__ out, int nblocks, double n_total)
{
    __shared__ double counts[NBINS];
    const int tid = threadIdx.x;

    if (tid < NBINS * 32) {
        const int bin = tid >> 5;
        const int j = tid & 31;
        unsigned int s = 0u;
        #pragma unroll 8
        for (int b = j; b < nblocks; b += 32)
            s += partials[b * NBINS + bin];
        #pragma unroll
        for (int m = 1; m < 32; m <<= 1)
            s += __shfl_xor(s, m, 32);
        if (j == 0) counts[bin] = (double)s;
    }
    __syncthreads();

    if (tid == 0) {
        double n1 = 0.0;
        #pragma unroll
        for (int c = 0; c < N_CLASSES; ++c)
            n1 += counts[c * N_GROUPS + 1];
        double n0 = n_total - n1;
        double acc = 0.0;
        #pragma unroll
        for (int c = 0; c < N_CLASSES; ++c) {
            double d = counts[c * N_GROUPS] / n0 - counts[c * N_GROUPS + 1] / n1;
            acc += d * d;
        }
        out[0] = (float)acc;
    }
}

extern "C" void kernel_launch(void* const* d_in, const int* in_sizes, int n_in,
                              void* d_out, int out_size, void* d_ws, size_t ws_size,
                              hipStream_t stream)
{
    const int* preds = (const int*)d_in[0];
    const int* attrs = (const int*)d_in[1];
    const int n = in_sizes[0];

    unsigned int* partials = (unsigned int*)d_ws;

    const int n4 = n / 4;
    const int span = BLOCK * ITEMS;                 // 1024 int4 per block-stage
    int grid = (n4 + span - 1) / span;
    if (grid > 1024) grid = 1024;                   // -> 4 pipelined stages per block at N=16.7M
    int max_grid = (int)(ws_size / (NBINS * sizeof(unsigned int)));
    if (grid > max_grid) grid = max_grid;
    if (grid < 1) grid = 1;

    spd_hist_kernel<<<grid, BLOCK, 0, stream>>>(preds, attrs, partials, n4, n);
    spd_finalize_kernel<<<1, 1024, 0, stream>>>(partials, (float*)d_out, grid, (double)n);
}